// Round 7
// baseline (44.517 us; speedup 1.0000x reference)
//
#include <hip/hip_runtime.h>
#include <cmath>

// Masked decode-GEMV: y[n] = sum_z m_z * x_z * W_t[z,n],
// m_z = (|x_z| * ||W_t[z,:]||_2 >= thresh).
//
// v4 — wave-autonomous rows, zero barriers in the main loop:
//   F: 256 blocks x 512 threads (1 block/CU, 8 waves). Each wave owns 7
//      complete contiguous rows; per row: 16x float4 reg load (2-deep
//      pipeline), lane-local squares, 6-step shfl_xor butterfly (every
//      lane gets the full norm -> wave-uniform mask), conditional FMA
//      into 16 float4 register accumulators. NO LDS, NO barriers, no
//      cross-wave coupling until a single 64 KB LDS combine epilogue.
//   C: reduce 256 partial vectors (4 MB) -> y.
// W is read from HBM exactly once (235 MB); no atomics anywhere.

#define ZDIM 14336
#define NDIM 4096
#define NF4  1024         // float4 per row
#define TPB  512          // 8 waves per block
#define NBLK 256          // 1 block per CU
#define RPB  (ZDIM / NBLK)   // 56 rows per block
#define RPW  (RPB / 8)       // 7 rows per wave

__global__ __launch_bounds__(TPB, 2) void fused_norm_gemv(
    const float* __restrict__ x,
    const float* __restrict__ Wt,
    const float* __restrict__ thresh,
    float* __restrict__ part) {
  const int t    = threadIdx.x;
  const int lane = t & 63;
  const int wv   = t >> 6;
  const int zw   = blockIdx.x * RPB + wv * RPW;  // this wave's first row

  const float th = thresh[0];
  const float4* __restrict__ W4 = reinterpret_cast<const float4*>(Wt) + lane;

  float4 acc[16];
  #pragma unroll
  for (int j = 0; j < 16; ++j) acc[j] = make_float4(0.f, 0.f, 0.f, 0.f);

  // two named row-register sets; all indexing compile-time (full unroll)
  float4 A[16], B[16];

#define LOADROW(S, r) do {                                                   \
    const float4* p_ = W4 + (size_t)(zw + (r)) * NF4;                        \
    _Pragma("unroll")                                                        \
    for (int j = 0; j < 16; ++j) S[j] = p_[j * 64];                          \
  } while (0)

#define COMPUTE(S, r) do {                                                   \
    float ss = 0.f;                                                          \
    _Pragma("unroll")                                                        \
    for (int j = 0; j < 16; ++j)                                             \
      ss += S[j].x * S[j].x + S[j].y * S[j].y                                \
          + S[j].z * S[j].z + S[j].w * S[j].w;                               \
    ss += __shfl_xor(ss, 1, 64);                                             \
    ss += __shfl_xor(ss, 2, 64);                                             \
    ss += __shfl_xor(ss, 4, 64);                                             \
    ss += __shfl_xor(ss, 8, 64);                                             \
    ss += __shfl_xor(ss, 16, 64);                                            \
    ss += __shfl_xor(ss, 32, 64);  /* butterfly: every lane has full sum */  \
    const float xz = x[zw + (r)];                                            \
    if (fabsf(xz) * sqrtf(ss) >= th) {  /* wave-uniform branch */            \
      _Pragma("unroll")                                                      \
      for (int j = 0; j < 16; ++j) {                                         \
        acc[j].x = fmaf(xz, S[j].x, acc[j].x);                               \
        acc[j].y = fmaf(xz, S[j].y, acc[j].y);                               \
        acc[j].z = fmaf(xz, S[j].z, acc[j].z);                               \
        acc[j].w = fmaf(xz, S[j].w, acc[j].w);                               \
      }                                                                      \
    }                                                                        \
  } while (0)

  // 2-deep software pipeline over 7 rows, zero barriers
  LOADROW(A, 0);
  LOADROW(B, 1);
  COMPUTE(A, 0);
  LOADROW(A, 2);
  COMPUTE(B, 1);
  LOADROW(B, 3);
  COMPUTE(A, 2);
  LOADROW(A, 4);
  COMPUTE(B, 3);
  LOADROW(B, 5);
  COMPUTE(A, 4);
  LOADROW(A, 6);
  COMPUTE(B, 5);
  COMPUTE(A, 6);
#undef LOADROW
#undef COMPUTE

  // ---- single cross-wave combine epilogue (the only barriers) ----
  __shared__ float4 lds4[4][NF4];   // 64 KB

  if (wv < 4) {
    #pragma unroll
    for (int j = 0; j < 16; ++j) lds4[wv][lane + 64 * j] = acc[j];
  }
  __syncthreads();
  if (wv >= 4) {
    #pragma unroll
    for (int j = 0; j < 16; ++j) {
      float4 v = lds4[wv - 4][lane + 64 * j];
      v.x += acc[j].x; v.y += acc[j].y; v.z += acc[j].z; v.w += acc[j].w;
      lds4[wv - 4][lane + 64 * j] = v;
    }
  }
  __syncthreads();

  float4* p4 = (float4*)part + (size_t)blockIdx.x * NF4;
  #pragma unroll
  for (int j = 0; j < 2; ++j) {
    const int c4 = t + j * 512;
    float4 s  = lds4[0][c4];
    const float4 v1 = lds4[1][c4];
    const float4 v2 = lds4[2][c4];
    const float4 v3 = lds4[3][c4];
    s.x += v1.x + v2.x + v3.x;
    s.y += v1.y + v2.y + v3.y;
    s.z += v1.z + v2.z + v3.z;
    s.w += v1.w + v2.w + v3.w;
    p4[c4] = s;
  }
}

// ---------------- reduce 256 partials -> y ----------------
// grid 256 blocks: block owns 4 float4 columns; thread (jg=t>>2, c=t&3)
// sums 4 partials, then two-stage LDS reduce 64 -> 8 -> 1.
__global__ __launch_bounds__(256) void reduce_parts(
    const float* __restrict__ part, float* __restrict__ y) {
  const int t  = threadIdx.x;
  const int c  = t & 3;
  const int jg = t >> 2;
  const int c4 = blockIdx.x * 4 + c;
  const float4* __restrict__ p4 = (const float4*)part;

  float4 s = {0.f, 0.f, 0.f, 0.f};
  #pragma unroll
  for (int jj = 0; jj < 4; ++jj) {
    const float4 v = p4[(size_t)(jg * 4 + jj) * NF4 + c4];
    s.x += v.x; s.y += v.y; s.z += v.z; s.w += v.w;
  }

  __shared__ float4 sh[64][4];
  sh[jg][c] = s;
  __syncthreads();
  if (jg < 8) {
    #pragma unroll
    for (int k = 1; k < 8; ++k) {
      const float4 v = sh[jg + 8 * k][c];
      s.x += v.x; s.y += v.y; s.z += v.z; s.w += v.w;
    }
    sh[jg][c] = s;
  }
  __syncthreads();
  if (jg == 0) {
    #pragma unroll
    for (int k = 1; k < 8; ++k) {
      const float4 v = sh[k][c];
      s.x += v.x; s.y += v.y; s.z += v.z; s.w += v.w;
    }
    ((float4*)y)[c4] = s;
  }
}

extern "C" void kernel_launch(void* const* d_in, const int* in_sizes, int n_in,
                              void* d_out, int out_size, void* d_ws, size_t ws_size,
                              hipStream_t stream) {
  const float* x      = (const float*)d_in[0];  // [1,1,Z]
  const float* Wt     = (const float*)d_in[1];  // [Z,N]
  const float* thresh = (const float*)d_in[2];  // [1]
  float* y            = (float*)d_out;          // [1,1,N]
  float* part         = (float*)d_ws;           // [NBLK][NDIM] = 4 MB

  fused_norm_gemv<<<NBLK, TPB, 0, stream>>>(x, Wt, thresh, part);
  reduce_parts<<<NF4 / 4, 256, 0, stream>>>(part, y);
}